// Round 8
// baseline (98.223 us; speedup 1.0000x reference)
//
#include <hip/hip_runtime.h>

typedef short bf16x8 __attribute__((ext_vector_type(8)));   // 8 bf16 = 4 VGPRs
typedef float f32x16 __attribute__((ext_vector_type(16)));  // MFMA 32x32 acc
typedef float f32x4  __attribute__((ext_vector_type(4)));

constexpr int B  = 16;
constexpr int H  = 128;
constexpr int CL = 2048;
constexpr int QL = 256;
constexpr int SPLITK5 = 8;
constexpr int K5SEG = CL / SPLITK5;   // 256
constexpr float SHIFT = 8.0f;         // exp shift (overflow-safe, |s| ~ O(6))

__device__ __forceinline__ unsigned short f2bf(float x) {
  unsigned u = __float_as_uint(x);
  u += 0x7fffu + ((u >> 16) & 1u);   // round-to-nearest-even
  return (unsigned short)(u >> 16);
}
__device__ __forceinline__ float bf2f(unsigned short u) {
  return __uint_as_float((unsigned)u << 16);
}

// ---------------- KT: fp32 -> bf16 linear + transposed copies + bias partials ----
// ctx path additionally writes output group 0 (exact fp32 copy, NT stores).
template<int L, bool SCALE, bool WOUT>
__device__ __forceinline__ void ktrans_body(
    const float* __restrict__ src, const float* __restrict__ wbias,
    const float* __restrict__ wscale,
    unsigned short* __restrict__ dlin, unsigned short* __restrict__ dT,
    float* __restrict__ pbias, float* __restrict__ outg0,
    int bxl, int h1, int b, int tid,
    unsigned short (*T)[72], float (*P)[64]) {
  const int c0 = bxl * 64;
  const int hh = tid >> 4;
  const int cc4 = (tid & 15) * 4;
  float4 part = make_float4(0.f, 0.f, 0.f, 0.f);
  #pragma unroll
  for (int it = 0; it < 4; ++it) {
    const int hrow = it * 16 + hh;
    const int h = h1 * 64 + hrow;
    float4 v = *(const float4*)&src[((size_t)b * H + h) * L + c0 + cc4];
    const float wb = wbias[h];
    part.x = fmaf(v.x, wb, part.x); part.y = fmaf(v.y, wb, part.y);
    part.z = fmaf(v.z, wb, part.z); part.w = fmaf(v.w, wb, part.w);
    if (WOUT) {
      f32x4 t;
      t[0] = v.x; t[1] = v.y; t[2] = v.z; t[3] = v.w;
      __builtin_nontemporal_store(
          t, (f32x4*)&outg0[((size_t)b * 4 * H + h) * (size_t)CL + c0 + cc4]);
    }
    ushort4 o;
    o.x = f2bf(v.x); o.y = f2bf(v.y); o.z = f2bf(v.z); o.w = f2bf(v.w);
    *(ushort4*)&dlin[((size_t)b * H + h) * L + c0 + cc4] = o;
    ushort4 ot;
    if (SCALE) {
      const float ws = wscale[h];
      ot.x = f2bf(v.x * ws); ot.y = f2bf(v.y * ws);
      ot.z = f2bf(v.z * ws); ot.w = f2bf(v.w * ws);
    } else {
      ot = o;
    }
    *(ushort4*)&T[hrow][cc4] = ot;
  }
  *(float4*)&P[hh][cc4] = part;
  __syncthreads();
  if (tid < 64) {
    float sum = 0.f;
    #pragma unroll
    for (int i = 0; i < 16; ++i) sum += P[i][tid];
    pbias[(size_t)h1 * B * L + (size_t)b * L + c0 + tid] = sum;
  }
  #pragma unroll
  for (int it = 0; it < 4; ++it) {
    int lin = it * 256 + tid;
    int c = lin >> 4, hc = (lin & 15) * 4;
    ushort4 o;
    o.x = T[hc + 0][c]; o.y = T[hc + 1][c];
    o.z = T[hc + 2][c]; o.w = T[hc + 3][c];
    *(ushort4*)&dT[((size_t)b * L + c0 + c) * H + h1 * 64 + hc] = o;
  }
}

__global__ __launch_bounds__(256) void ktrans_all(
    const float* __restrict__ ctx, const float* __restrict__ qry,
    const float* __restrict__ w,
    unsigned short* __restrict__ ctx_bf, unsigned short* __restrict__ ctxwT,
    unsigned short* __restrict__ qry_bf, unsigned short* __restrict__ qryT,
    float* __restrict__ pct, float* __restrict__ pqt,
    float* __restrict__ out) {
  __shared__ unsigned short T[64][72];
  __shared__ float P[16][64];
  const int h1 = blockIdx.y, b = blockIdx.z, tid = threadIdx.x;
  const int bx = blockIdx.x;
  if (bx < CL / 64) {
    ktrans_body<CL, true, true>(ctx, w + H, w + 2 * H, ctx_bf, ctxwT, pct, out,
                                bx, h1, b, tid, T, P);
  } else {
    ktrans_body<QL, false, false>(qry, w, w, qry_bf, qryT, pqt, nullptr,
                                  bx - CL / 64, h1, b, tid, T, P);
  }
}

// ---------------- K2C: MFMA score (M=q, N=c) + column exp + s2u + Lpart ----
__global__ __launch_bounds__(512) void k2_col(
    const unsigned short* __restrict__ ctxwT, const unsigned short* __restrict__ qryT,
    const float* __restrict__ pct, const float* __restrict__ pqt,
    const int* __restrict__ cmask,
    unsigned short* __restrict__ s2u, float* __restrict__ Lpart) {
  __shared__ unsigned short tile[10240];   // [256 q][40 c]
  const int cblk = blockIdx.x;
  const int c0 = cblk * 32;
  const int b = blockIdx.y;
  const int tid = threadIdx.x;
  const int w = tid >> 6;
  const int l = tid & 63;
  const int lr = l & 31, hi = l >> 5;
  const int q0 = w * 32;
  const int c = c0 + lr;

  const unsigned short* ap = qryT + ((size_t)b * QL + q0 + lr) * H + hi * 8;
  const unsigned short* bp = ctxwT + ((size_t)b * CL + c) * H + hi * 8;
  f32x16 acc = {};
  #pragma unroll
  for (int k = 0; k < H; k += 16) {
    bf16x8 af = *(const bf16x8*)(ap + k);
    bf16x8 bf_ = *(const bf16x8*)(bp + k);
    acc = __builtin_amdgcn_mfma_f32_32x32x16_bf16(af, bf_, acc, 0, 0, 0);
  }

  const float ct = pct[b * CL + c] + pct[B * CL + b * CL + c];
  const bool cm = cmask[b * CL + c] > 0;
  #pragma unroll
  for (int g = 0; g < 4; ++g) {
    const int qbase = q0 + 4 * hi + 8 * g;
    float4 qa = *(const float4*)&pqt[b * QL + qbase];
    float4 qb = *(const float4*)&pqt[B * QL + b * QL + qbase];
    ushort4 o;
    o.x = f2bf(cm ? __expf(acc[4 * g + 0] + ct + qa.x + qb.x - SHIFT) : 0.f);
    o.y = f2bf(cm ? __expf(acc[4 * g + 1] + ct + qa.y + qb.y - SHIFT) : 0.f);
    o.z = f2bf(cm ? __expf(acc[4 * g + 2] + ct + qa.z + qb.z - SHIFT) : 0.f);
    o.w = f2bf(cm ? __expf(acc[4 * g + 3] + ct + qa.w + qb.w - SHIFT) : 0.f);
    tile[(qbase + 0) * 40 + lr] = o.x;
    tile[(qbase + 1) * 40 + lr] = o.y;
    tile[(qbase + 2) * 40 + lr] = o.z;
    tile[(qbase + 3) * 40 + lr] = o.w;
  }
  __syncthreads();
  {  // coalesced s2u copy-out + fused column partial sums
    const int q = tid >> 1, co = (tid & 1) * 16;
    bf16x8 v0 = *(const bf16x8*)&tile[q * 40 + co];
    bf16x8 v1 = *(const bf16x8*)&tile[q * 40 + co + 8];
    float cs = 0.f;
    #pragma unroll
    for (int i2 = 0; i2 < 8; ++i2) {
      cs += bf2f((unsigned short)v0[i2]);
      cs += bf2f((unsigned short)v1[i2]);
    }
    cs += __shfl_xor(cs, 1);
    unsigned short* op = s2u + ((size_t)b * QL + q) * CL + c0 + co;
    *(bf16x8*)op = v0;
    *(bf16x8*)(op + 8) = v1;
    if ((tid & 1) == 0) Lpart[((size_t)b * 64 + cblk) * QL + q] = cs;
  }
}

// ---------------- K5: MFMA tpart[seg][b][q][h] = sum_{c in seg} s2u[q,c]*ctx[h,c] ---
__global__ __launch_bounds__(256, 4) void k5_tpart(
    const unsigned short* __restrict__ s2u,
    const unsigned short* __restrict__ ctxbf,
    unsigned short* __restrict__ tpart) {
  const int q0 = blockIdx.x * 32;
  const int seg = blockIdx.y;
  const int b = blockIdx.z;
  const int w = threadIdx.x >> 6, l = threadIdx.x & 63;
  const int h0 = w * 32;
  const int lr = l & 31, lg = l >> 5;
  const unsigned short* ap = s2u + ((size_t)b * QL + q0 + lr) * CL + seg * K5SEG + lg * 8;
  const unsigned short* bp = ctxbf + ((size_t)b * H + h0 + lr) * CL + seg * K5SEG + lg * 8;
  f32x16 acc = {};
  #pragma unroll
  for (int k = 0; k < K5SEG; k += 16) {
    bf16x8 af = *(const bf16x8*)(ap + k);
    bf16x8 bfr = *(const bf16x8*)(bp + k);
    acc = __builtin_amdgcn_mfma_f32_32x32x16_bf16(af, bfr, acc, 0, 0, 0);
  }
  unsigned short* tp = tpart + (size_t)(seg * B + b) * QL * H;
  #pragma unroll
  for (int r = 0; r < 16; ++r) {
    int qrow = (r & 3) + 8 * (r >> 2) + 4 * lg;
    tp[(size_t)(q0 + qrow) * H + h0 + lr] = f2bf(acc[r]);
  }
}

// ---------------- K5b: cinv from Lpart + reduce tpart, write tT_bf[b][h][q] ----
// grid (QL/64, H/32, B) = 256 blocks.
__global__ __launch_bounds__(256) void k5b_treduce(
    const unsigned short* __restrict__ tpart, const float* __restrict__ Lpart,
    unsigned short* __restrict__ tTbf) {
  __shared__ unsigned short lds[32 * 66];
  __shared__ float csum[4][64];
  __shared__ float cinv_s[64];
  const int q0 = blockIdx.x * 64, h0 = blockIdx.y * 32, b = blockIdx.z;
  const int tid = threadIdx.x;
  {  // cinv for this block's 64 q's
    const int qq = tid & 63, part = tid >> 6;
    float Ls = 0.f;
    #pragma unroll
    for (int k = 0; k < 16; ++k)
      Ls += Lpart[((size_t)b * 64 + part * 16 + k) * QL + q0 + qq];
    csum[part][qq] = Ls;
  }
  __syncthreads();
  if (tid < 64)
    cinv_s[tid] = 1.0f / (csum[0][tid] + csum[1][tid] + csum[2][tid] + csum[3][tid]);
  __syncthreads();
  for (int lin = tid; lin < 64 * 32; lin += 256) {
    int q = lin >> 5, h = lin & 31;
    float v = 0.f;
    #pragma unroll
    for (int sgt = 0; sgt < SPLITK5; ++sgt)
      v += bf2f(tpart[((size_t)(sgt * B + b) * QL + q0 + q) * H + h0 + h]);
    lds[h * 66 + q] = f2bf(v * cinv_s[q]);
  }
  __syncthreads();
  for (int lin = tid; lin < 32 * 64; lin += 256) {
    int h = lin >> 6, q = lin & 63;
    tTbf[((size_t)b * H + h0 + h) * QL + q0 + q] = lds[h * 66 + q];
  }
}

// ---------------- K6: recompute score + shifted-exp row softmax + dual GEMM ----
// grid (CL/32, B), block 256 (4 waves). Groups 1..3 only (group 0 from ktrans).
// No row-max pass: e = exp(s-SHIFT); rinv = 1/sum. Scores never stored (no spill).
__global__ __launch_bounds__(256) void k6_out(
    const unsigned short* __restrict__ ctxwT, const unsigned short* __restrict__ qryT,
    const unsigned short* __restrict__ qrybf, const unsigned short* __restrict__ tTbf,
    const unsigned short* __restrict__ ctxbf,
    const float* __restrict__ pct, const float* __restrict__ pqt,
    const int* __restrict__ qmask, float* __restrict__ out) {
  __shared__ unsigned short tile[32 * 264];   // [c 32][q 264] unnormalized exp
  __shared__ float stats[32][4];
  const int c0 = blockIdx.x * 32;
  const int b = blockIdx.y;
  const int tid = threadIdx.x;
  const int w = tid >> 6, l = tid & 63;
  const int lr = l & 31, hi = l >> 5;
  const int c = c0 + lr;
  const int h0 = w * 32;

  // shared B-frags: ctxwT row c (same for both score q-tiles)
  const unsigned short* bp = ctxwT + ((size_t)b * CL + c) * H + hi * 8;
  bf16x8 bfrag[8];
  #pragma unroll
  for (int k = 0; k < 8; ++k) bfrag[k] = *(const bf16x8*)(bp + k * 16);

  const float ct = pct[b * CL + c] + pct[B * CL + b * CL + c];

  // score MFMA + immediate shifted exp -> LDS tile + row-sum accumulation
  float rsum = 0.f;
  #pragma unroll
  for (int t2 = 0; t2 < 2; ++t2) {
    const int q0t = (w * 2 + t2) * 32;
    const unsigned short* ap = qryT + ((size_t)b * QL + q0t + lr) * H + hi * 8;
    f32x16 acc = {};
    #pragma unroll
    for (int k = 0; k < 8; ++k)
      acc = __builtin_amdgcn_mfma_f32_32x32x16_bf16(
          *(const bf16x8*)(ap + k * 16), bfrag[k], acc, 0, 0, 0);
    #pragma unroll
    for (int g = 0; g < 4; ++g) {
      const int qbase = q0t + 4 * hi + 8 * g;
      float4 qa = *(const float4*)&pqt[b * QL + qbase];
      float4 qb = *(const float4*)&pqt[B * QL + b * QL + qbase];
      int4 m4 = *(const int4*)&qmask[b * QL + qbase];
      float e0 = m4.x > 0 ? __expf(acc[4 * g + 0] + ct + qa.x + qb.x - SHIFT) : 0.f;
      float e1 = m4.y > 0 ? __expf(acc[4 * g + 1] + ct + qa.y + qb.y - SHIFT) : 0.f;
      float e2 = m4.z > 0 ? __expf(acc[4 * g + 2] + ct + qa.z + qb.z - SHIFT) : 0.f;
      float e3 = m4.w > 0 ? __expf(acc[4 * g + 3] + ct + qa.w + qb.w - SHIFT) : 0.f;
      rsum += e0 + e1 + e2 + e3;
      ushort4 o;
      o.x = f2bf(e0); o.y = f2bf(e1); o.z = f2bf(e2); o.w = f2bf(e3);
      *(ushort4*)&tile[lr * 264 + qbase] = o;
    }
  }
  rsum += __shfl_xor(rsum, 32);
  if (hi == 0) stats[lr][w] = rsum;

  // batched A-fragment loads (independent of tile) + epilogue ctx values
  const unsigned short* a1p = qrybf + ((size_t)b * H + h0 + lr) * QL + hi * 8;
  const unsigned short* a2p = tTbf + ((size_t)b * H + h0 + lr) * QL + hi * 8;
  bf16x8 a1f[16], a2f[16];
  #pragma unroll
  for (int kc = 0; kc < 16; ++kc) {
    a1f[kc] = *(const bf16x8*)(a1p + kc * 16);
    a2f[kc] = *(const bf16x8*)(a2p + kc * 16);
  }
  unsigned short cvu[16];
  {
    const unsigned short* cvp = ctxbf + (size_t)b * H * CL + c;
    #pragma unroll
    for (int r = 0; r < 16; ++r) {
      const int h = h0 + (r & 3) + 8 * (r >> 2) + 4 * hi;
      cvu[r] = cvp[(size_t)h * CL];
    }
  }
  __syncthreads();   // tile + stats ready
  const float rinv = 1.0f / (stats[lr][0] + stats[lr][1] + stats[lr][2] + stats[lr][3]);

  // dual GEMM: aT[h,c] = sum_q qry[h,q]*e[c,q];  bT[h,c] = sum_q tT[h,q]*e[c,q]
  f32x16 accA = {}, accB = {};
  #pragma unroll
  for (int kc = 0; kc < 16; ++kc) {
    bf16x8 bfr = *(const bf16x8*)&tile[lr * 264 + kc * 16 + hi * 8];
    accA = __builtin_amdgcn_mfma_f32_32x32x16_bf16(a1f[kc], bfr, accA, 0, 0, 0);
    accB = __builtin_amdgcn_mfma_f32_32x32x16_bf16(a2f[kc], bfr, accB, 0, 0, 0);
  }
  float* ob = out + (size_t)b * 4 * H * CL;
  #pragma unroll
  for (int r = 0; r < 16; ++r) {
    const int h = h0 + (r & 3) + 8 * (r >> 2) + 4 * hi;
    const float cv = bf2f(cvu[r]);
    const float av = accA[r] * rinv;
    const float bv = accB[r] * rinv;
    __builtin_nontemporal_store(av, &ob[(size_t)(H + h) * CL + c]);
    __builtin_nontemporal_store(cv * av, &ob[(size_t)(2 * H + h) * CL + c]);
    __builtin_nontemporal_store(cv * bv, &ob[(size_t)(3 * H + h) * CL + c]);
  }
}

extern "C" void kernel_launch(void* const* d_in, const int* in_sizes, int n_in,
                              void* d_out, int out_size, void* d_ws, size_t ws_size,
                              hipStream_t stream) {
  const float* context  = (const float*)d_in[0];
  const float* question = (const float*)d_in[1];
  const int*   c_mask   = (const int*)d_in[2];
  const int*   q_mask   = (const int*)d_in[3];
  const float* w        = (const float*)d_in[4];
  float* out = (float*)d_out;

  char* ws = (char*)d_ws;
  size_t off = 0;
  auto alloc = [&](size_t bytes) -> void* {
    void* p = ws + off;
    off += (bytes + 255) & ~(size_t)255;
    return p;
  };
  unsigned short* ctx_bf = (unsigned short*)alloc((size_t)B * H * CL * 2);    // 8.4 MB
  unsigned short* ctxwT  = (unsigned short*)alloc((size_t)B * CL * H * 2);    // 8.4 MB
  unsigned short* qry_bf = (unsigned short*)alloc((size_t)B * H * QL * 2);    // 1.05 MB
  unsigned short* qryT   = (unsigned short*)alloc((size_t)B * QL * H * 2);    // 1.05 MB
  unsigned short* s2u    = (unsigned short*)alloc((size_t)B * QL * CL * 2);   // 16.8 MB
  unsigned short* tpart  = (unsigned short*)alloc((size_t)SPLITK5 * B * QL * H * 2); // 8.4 MB
  unsigned short* tT_bf  = (unsigned short*)alloc((size_t)B * H * QL * 2);    // 1.05 MB
  float* pct   = (float*)alloc((size_t)2 * B * CL * sizeof(float));
  float* pqt   = (float*)alloc((size_t)2 * B * QL * sizeof(float));
  float* Lpart = (float*)alloc((size_t)B * 64 * QL * sizeof(float));          // 1 MB

  ktrans_all<<<dim3(CL / 64 + QL / 64, H / 64, B), dim3(256), 0, stream>>>(
      context, question, w, ctx_bf, ctxwT, qry_bf, qryT, pct, pqt, out);

  k2_col<<<dim3(CL / 32, B), dim3(512), 0, stream>>>(
      ctxwT, qryT, pct, pqt, c_mask, s2u, Lpart);

  k5_tpart<<<dim3(QL / 32, SPLITK5, B), dim3(256), 0, stream>>>(
      s2u, ctx_bf, tpart);

  k5b_treduce<<<dim3(QL / 64, H / 32, B), dim3(256), 0, stream>>>(
      tpart, Lpart, tT_bf);

  k6_out<<<dim3(CL / 32, B), dim3(256), 0, stream>>>(
      ctxwT, qryT, qry_bf, tT_bf, ctx_bf, pct, pqt, q_mask, out);
}

// Round 9
// 87.968 us; speedup vs baseline: 1.1166x; 1.1166x over previous
//
#include <hip/hip_runtime.h>

typedef short bf16x8 __attribute__((ext_vector_type(8)));   // 8 bf16 = 4 VGPRs
typedef float f32x16 __attribute__((ext_vector_type(16)));  // MFMA 32x32 acc
typedef float f32x4  __attribute__((ext_vector_type(4)));

constexpr int B  = 16;
constexpr int H  = 128;
constexpr int CL = 2048;
constexpr int QL = 256;
constexpr int SPLITK5 = 8;
constexpr int K5SEG = CL / SPLITK5;   // 256
constexpr float SHIFT = 8.0f;         // exp shift (overflow-safe, |s| ~ O(6))

__device__ __forceinline__ unsigned short f2bf(float x) {
  unsigned u = __float_as_uint(x);
  u += 0x7fffu + ((u >> 16) & 1u);   // round-to-nearest-even
  return (unsigned short)(u >> 16);
}
__device__ __forceinline__ float bf2f(unsigned short u) {
  return __uint_as_float((unsigned)u << 16);
}

// ---------------- KT: fp32 -> bf16 linear + transposed copies + bias partials ----
// ctx path additionally writes output group 0 (exact fp32 copy, NT stores).
template<int L, bool SCALE, bool WOUT>
__device__ __forceinline__ void ktrans_body(
    const float* __restrict__ src, const float* __restrict__ wbias,
    const float* __restrict__ wscale,
    unsigned short* __restrict__ dlin, unsigned short* __restrict__ dT,
    float* __restrict__ pbias, float* __restrict__ outg0,
    int bxl, int h1, int b, int tid,
    unsigned short (*T)[72], float (*P)[64]) {
  const int c0 = bxl * 64;
  const int hh = tid >> 4;
  const int cc4 = (tid & 15) * 4;
  float4 part = make_float4(0.f, 0.f, 0.f, 0.f);
  #pragma unroll
  for (int it = 0; it < 4; ++it) {
    const int hrow = it * 16 + hh;
    const int h = h1 * 64 + hrow;
    float4 v = *(const float4*)&src[((size_t)b * H + h) * L + c0 + cc4];
    const float wb = wbias[h];
    part.x = fmaf(v.x, wb, part.x); part.y = fmaf(v.y, wb, part.y);
    part.z = fmaf(v.z, wb, part.z); part.w = fmaf(v.w, wb, part.w);
    if (WOUT) {
      f32x4 t;
      t[0] = v.x; t[1] = v.y; t[2] = v.z; t[3] = v.w;
      __builtin_nontemporal_store(
          t, (f32x4*)&outg0[((size_t)b * 4 * H + h) * (size_t)CL + c0 + cc4]);
    }
    ushort4 o;
    o.x = f2bf(v.x); o.y = f2bf(v.y); o.z = f2bf(v.z); o.w = f2bf(v.w);
    *(ushort4*)&dlin[((size_t)b * H + h) * L + c0 + cc4] = o;
    ushort4 ot;
    if (SCALE) {
      const float ws = wscale[h];
      ot.x = f2bf(v.x * ws); ot.y = f2bf(v.y * ws);
      ot.z = f2bf(v.z * ws); ot.w = f2bf(v.w * ws);
    } else {
      ot = o;
    }
    *(ushort4*)&T[hrow][cc4] = ot;
  }
  *(float4*)&P[hh][cc4] = part;
  __syncthreads();
  if (tid < 64) {
    float sum = 0.f;
    #pragma unroll
    for (int i = 0; i < 16; ++i) sum += P[i][tid];
    pbias[(size_t)h1 * B * L + (size_t)b * L + c0 + tid] = sum;
  }
  #pragma unroll
  for (int it = 0; it < 4; ++it) {
    int lin = it * 256 + tid;
    int c = lin >> 4, hc = (lin & 15) * 4;
    ushort4 o;
    o.x = T[hc + 0][c]; o.y = T[hc + 1][c];
    o.z = T[hc + 2][c]; o.w = T[hc + 3][c];
    *(ushort4*)&dT[((size_t)b * L + c0 + c) * H + h1 * 64 + hc] = o;
  }
}

__global__ __launch_bounds__(256) void ktrans_all(
    const float* __restrict__ ctx, const float* __restrict__ qry,
    const float* __restrict__ w,
    unsigned short* __restrict__ ctx_bf, unsigned short* __restrict__ ctxwT,
    unsigned short* __restrict__ qry_bf, unsigned short* __restrict__ qryT,
    float* __restrict__ pct, float* __restrict__ pqt,
    float* __restrict__ out) {
  __shared__ unsigned short T[64][72];
  __shared__ float P[16][64];
  const int h1 = blockIdx.y, b = blockIdx.z, tid = threadIdx.x;
  const int bx = blockIdx.x;
  if (bx < CL / 64) {
    ktrans_body<CL, true, true>(ctx, w + H, w + 2 * H, ctx_bf, ctxwT, pct, out,
                                bx, h1, b, tid, T, P);
  } else {
    ktrans_body<QL, false, false>(qry, w, w, qry_bf, qryT, pqt, nullptr,
                                  bx - CL / 64, h1, b, tid, T, P);
  }
}

// ---------------- K2: MFMA score ONCE + shifted exp; emit s1u[c][q], s2u[q][c],
// rsum[b][c] (qmasked row sums), Lpart (cmasked col partial sums) ----------------
// grid (CL/32, B), block 512 (8 waves; wave w owns q-tile w).
__global__ __launch_bounds__(512) void k2_score2(
    const unsigned short* __restrict__ ctxwT, const unsigned short* __restrict__ qryT,
    const float* __restrict__ pct, const float* __restrict__ pqt,
    const int* __restrict__ cmask, const int* __restrict__ qmask,
    unsigned short* __restrict__ s1u, unsigned short* __restrict__ s2u,
    float* __restrict__ rsum_g, float* __restrict__ Lpart) {
  __shared__ unsigned short tile[10240];   // s1: [32 c][264 q] (8448); s2: [256 q][40 c]
  __shared__ float stats[32][8];
  const int cblk = blockIdx.x;
  const int c0 = cblk * 32;
  const int b = blockIdx.y;
  const int tid = threadIdx.x;
  const int w = tid >> 6;
  const int l = tid & 63;
  const int lr = l & 31, hi = l >> 5;
  const int q0 = w * 32;
  const int c = c0 + lr;

  // score MFMA: A = qryT rows (M=q), B = ctxwT rows (N=c), K=H=128
  const unsigned short* ap = qryT + ((size_t)b * QL + q0 + lr) * H + hi * 8;
  const unsigned short* bp = ctxwT + ((size_t)b * CL + c) * H + hi * 8;
  f32x16 acc = {};
  #pragma unroll
  for (int k = 0; k < H; k += 16) {
    bf16x8 af = *(const bf16x8*)(ap + k);
    bf16x8 bf_ = *(const bf16x8*)(bp + k);
    acc = __builtin_amdgcn_mfma_f32_32x32x16_bf16(af, bf_, acc, 0, 0, 0);
  }

  const float ct = pct[b * CL + c] + pct[B * CL + b * CL + c];
  const bool cm = cmask[b * CL + c] > 0;

  float e[16];       // raw exp(s - SHIFT)
  unsigned qmb = 0;  // per-q mask bits
  float rs = 0.f;    // qmasked row-sum contribution
  #pragma unroll
  for (int g = 0; g < 4; ++g) {
    const int qbase = q0 + 4 * hi + 8 * g;
    float4 qa = *(const float4*)&pqt[b * QL + qbase];
    float4 qb = *(const float4*)&pqt[B * QL + b * QL + qbase];
    int4 m4 = *(const int4*)&qmask[b * QL + qbase];
    e[4 * g + 0] = __expf(acc[4 * g + 0] + ct + qa.x + qb.x - SHIFT);
    e[4 * g + 1] = __expf(acc[4 * g + 1] + ct + qa.y + qb.y - SHIFT);
    e[4 * g + 2] = __expf(acc[4 * g + 2] + ct + qa.z + qb.z - SHIFT);
    e[4 * g + 3] = __expf(acc[4 * g + 3] + ct + qa.w + qb.w - SHIFT);
    qmb |= (m4.x > 0 ? 1u : 0u) << (4 * g + 0);
    qmb |= (m4.y > 0 ? 1u : 0u) << (4 * g + 1);
    qmb |= (m4.z > 0 ? 1u : 0u) << (4 * g + 2);
    qmb |= (m4.w > 0 ? 1u : 0u) << (4 * g + 3);
  }

  // ---- s1 path: qmasked values into [32 c][264 q] tile + row sums ----
  #pragma unroll
  for (int g = 0; g < 4; ++g) {
    ushort4 o;
    #pragma unroll
    for (int j = 0; j < 4; ++j) {
      const float ev = ((qmb >> (4 * g + j)) & 1u) ? e[4 * g + j] : 0.f;
      rs += ev;
      (&o.x)[j] = f2bf(ev);
    }
    *(ushort4*)&tile[lr * 264 + q0 + 4 * hi + 8 * g] = o;
  }
  rs += __shfl_xor(rs, 32);
  if (hi == 0) stats[lr][w] = rs;
  __syncthreads();
  if (tid < 32) {
    float s = 0.f;
    #pragma unroll
    for (int ww = 0; ww < 8; ++ww) s += stats[tid][ww];
    rsum_g[b * CL + c0 + tid] = s;
  }
  {  // coalesced s1u copy-out: 32 c x 256 q
    const int row = tid >> 4, qo = (tid & 15) * 16;
    bf16x8 v0 = *(const bf16x8*)&tile[row * 264 + qo];
    bf16x8 v1 = *(const bf16x8*)&tile[row * 264 + qo + 8];
    unsigned short* op = s1u + ((size_t)b * CL + c0 + row) * QL + qo;
    *(bf16x8*)op = v0;
    *(bf16x8*)(op + 8) = v1;
  }
  __syncthreads();

  // ---- s2 path: cmasked values into [256 q][40 c] tile ----
  #pragma unroll
  for (int g = 0; g < 4; ++g) {
    const int qbase = q0 + 4 * hi + 8 * g;
    #pragma unroll
    for (int j = 0; j < 4; ++j)
      tile[(qbase + j) * 40 + lr] = f2bf(cm ? e[4 * g + j] : 0.f);
  }
  __syncthreads();
  {  // coalesced s2u copy-out + fused column partial sums
    const int q = tid >> 1, co = (tid & 1) * 16;
    bf16x8 v0 = *(const bf16x8*)&tile[q * 40 + co];
    bf16x8 v1 = *(const bf16x8*)&tile[q * 40 + co + 8];
    float cs = 0.f;
    #pragma unroll
    for (int i2 = 0; i2 < 8; ++i2) {
      cs += bf2f((unsigned short)v0[i2]);
      cs += bf2f((unsigned short)v1[i2]);
    }
    cs += __shfl_xor(cs, 1);
    unsigned short* op = s2u + ((size_t)b * QL + q) * CL + c0 + co;
    *(bf16x8*)op = v0;
    *(bf16x8*)(op + 8) = v1;
    if ((tid & 1) == 0) Lpart[((size_t)b * 64 + cblk) * QL + q] = cs;
  }
}

// ---------------- K5: MFMA tpart[seg][b][q][h] = sum_{c in seg} s2u[q,c]*ctx[h,c] ---
__global__ __launch_bounds__(256, 4) void k5_tpart(
    const unsigned short* __restrict__ s2u,
    const unsigned short* __restrict__ ctxbf,
    unsigned short* __restrict__ tpart) {
  const int q0 = blockIdx.x * 32;
  const int seg = blockIdx.y;
  const int b = blockIdx.z;
  const int w = threadIdx.x >> 6, l = threadIdx.x & 63;
  const int h0 = w * 32;
  const int lr = l & 31, lg = l >> 5;
  const unsigned short* ap = s2u + ((size_t)b * QL + q0 + lr) * CL + seg * K5SEG + lg * 8;
  const unsigned short* bp = ctxbf + ((size_t)b * H + h0 + lr) * CL + seg * K5SEG + lg * 8;
  f32x16 acc = {};
  #pragma unroll
  for (int k = 0; k < K5SEG; k += 16) {
    bf16x8 af = *(const bf16x8*)(ap + k);
    bf16x8 bfr = *(const bf16x8*)(bp + k);
    acc = __builtin_amdgcn_mfma_f32_32x32x16_bf16(af, bfr, acc, 0, 0, 0);
  }
  unsigned short* tp = tpart + (size_t)(seg * B + b) * QL * H;
  #pragma unroll
  for (int r = 0; r < 16; ++r) {
    int qrow = (r & 3) + 8 * (r >> 2) + 4 * lg;
    tp[(size_t)(q0 + qrow) * H + h0 + lr] = f2bf(acc[r]);
  }
}

// ---------------- K5b: cinv from Lpart + reduce tpart, write tT_bf[b][h][q] ----
// grid (QL/64, H/32, B) = 256 blocks.
__global__ __launch_bounds__(256) void k5b_treduce(
    const unsigned short* __restrict__ tpart, const float* __restrict__ Lpart,
    unsigned short* __restrict__ tTbf) {
  __shared__ unsigned short lds[32 * 66];
  __shared__ float csum[4][64];
  __shared__ float cinv_s[64];
  const int q0 = blockIdx.x * 64, h0 = blockIdx.y * 32, b = blockIdx.z;
  const int tid = threadIdx.x;
  {  // cinv for this block's 64 q's
    const int qq = tid & 63, part = tid >> 6;
    float Ls = 0.f;
    #pragma unroll
    for (int k = 0; k < 16; ++k)
      Ls += Lpart[((size_t)b * 64 + part * 16 + k) * QL + q0 + qq];
    csum[part][qq] = Ls;
  }
  __syncthreads();
  if (tid < 64)
    cinv_s[tid] = 1.0f / (csum[0][tid] + csum[1][tid] + csum[2][tid] + csum[3][tid]);
  __syncthreads();
  for (int lin = tid; lin < 64 * 32; lin += 256) {
    int q = lin >> 5, h = lin & 31;
    float v = 0.f;
    #pragma unroll
    for (int sgt = 0; sgt < SPLITK5; ++sgt)
      v += bf2f(tpart[((size_t)(sgt * B + b) * QL + q0 + q) * H + h0 + h]);
    lds[h * 66 + q] = f2bf(v * cinv_s[q]);
  }
  __syncthreads();
  for (int lin = tid; lin < 32 * 64; lin += 256) {
    int h = lin >> 6, q = lin & 63;
    tTbf[((size_t)b * H + h0 + h) * QL + q0 + q] = lds[h * 66 + q];
  }
}

// ---------------- KB: clean dual-GEMM from s1u + fused output (groups 1..3) ----
// grid (CL/64, B), block 512 (8 waves). Single LDS stage, 1 barrier, K=256.
// wave w: h0=(w&3)*32, c-half=(w>>2)*32. Output 128h x 64c per block.
__global__ __launch_bounds__(512) void kb_out(
    const unsigned short* __restrict__ s1u,
    const unsigned short* __restrict__ qrybf, const unsigned short* __restrict__ tTbf,
    const unsigned short* __restrict__ ctxbf, const float* __restrict__ rsum_g,
    float* __restrict__ out) {
  __shared__ unsigned short Ps[64 * 264];   // [64 c][264 q] P-tile
  const int c0 = blockIdx.x * 64;
  const int b = blockIdx.y;
  const int tid = threadIdx.x;
  const int w = tid >> 6, l = tid & 63;
  const int lr = l & 31, hi = l >> 5;
  const int h0 = (w & 3) * 32;
  const int ch = (w >> 2) * 32;
  const int c = c0 + ch + lr;

  // stage P-tile: 64 rows x 512 B, coalesced
  #pragma unroll
  for (int p = 0; p < 4; ++p) {
    const int idx = p * 512 + tid;
    const int row = idx >> 5, colb = (idx & 31) * 8;
    bf16x8 v = *(const bf16x8*)&s1u[((size_t)b * CL + c0 + row) * QL + colb];
    *(bf16x8*)&Ps[row * 264 + colb] = v;
  }

  const float rinv = 1.0f / rsum_g[b * CL + c];

  // epilogue ctx values (overlap with staging)
  unsigned short cvu[16];
  {
    const unsigned short* cvp = ctxbf + (size_t)b * H * CL + c;
    #pragma unroll
    for (int r = 0; r < 16; ++r) {
      const int h = h0 + (r & 3) + 8 * (r >> 2) + 4 * hi;
      cvu[r] = cvp[(size_t)h * CL];
    }
  }
  __syncthreads();

  // dual GEMM: aT[h,c] = sum_q qry[h,q]*P[c,q]; bT[h,c] = sum_q tT[h,q]*P[c,q]
  const unsigned short* a1p = qrybf + ((size_t)b * H + h0 + lr) * QL + hi * 8;
  const unsigned short* a2p = tTbf + ((size_t)b * H + h0 + lr) * QL + hi * 8;
  f32x16 accA = {}, accB = {};
  #pragma unroll
  for (int kc = 0; kc < 16; ++kc) {
    bf16x8 pb = *(const bf16x8*)&Ps[(ch + lr) * 264 + kc * 16 + hi * 8];
    bf16x8 a1 = *(const bf16x8*)(a1p + kc * 16);
    bf16x8 a2 = *(const bf16x8*)(a2p + kc * 16);
    accA = __builtin_amdgcn_mfma_f32_32x32x16_bf16(a1, pb, accA, 0, 0, 0);
    accB = __builtin_amdgcn_mfma_f32_32x32x16_bf16(a2, pb, accB, 0, 0, 0);
  }
  float* ob = out + (size_t)b * 4 * H * CL;
  #pragma unroll
  for (int r = 0; r < 16; ++r) {
    const int h = h0 + (r & 3) + 8 * (r >> 2) + 4 * hi;
    const float cv = bf2f(cvu[r]);
    const float av = accA[r] * rinv;
    const float bv = accB[r] * rinv;
    __builtin_nontemporal_store(av, &ob[(size_t)(H + h) * CL + c]);
    __builtin_nontemporal_store(cv * av, &ob[(size_t)(2 * H + h) * CL + c]);
    __builtin_nontemporal_store(cv * bv, &ob[(size_t)(3 * H + h) * CL + c]);
  }
}

extern "C" void kernel_launch(void* const* d_in, const int* in_sizes, int n_in,
                              void* d_out, int out_size, void* d_ws, size_t ws_size,
                              hipStream_t stream) {
  const float* context  = (const float*)d_in[0];
  const float* question = (const float*)d_in[1];
  const int*   c_mask   = (const int*)d_in[2];
  const int*   q_mask   = (const int*)d_in[3];
  const float* w        = (const float*)d_in[4];
  float* out = (float*)d_out;

  char* ws = (char*)d_ws;
  size_t off = 0;
  auto alloc = [&](size_t bytes) -> void* {
    void* p = ws + off;
    off += (bytes + 255) & ~(size_t)255;
    return p;
  };
  unsigned short* ctx_bf = (unsigned short*)alloc((size_t)B * H * CL * 2);    // 8.4 MB
  unsigned short* ctxwT  = (unsigned short*)alloc((size_t)B * CL * H * 2);    // 8.4 MB
  unsigned short* qry_bf = (unsigned short*)alloc((size_t)B * H * QL * 2);    // 1.05 MB
  unsigned short* qryT   = (unsigned short*)alloc((size_t)B * QL * H * 2);    // 1.05 MB
  unsigned short* s1u    = (unsigned short*)alloc((size_t)B * CL * QL * 2);   // 16.8 MB
  unsigned short* s2u    = (unsigned short*)alloc((size_t)B * QL * CL * 2);   // 16.8 MB
  unsigned short* tpart  = (unsigned short*)alloc((size_t)SPLITK5 * B * QL * H * 2); // 8.4 MB
  unsigned short* tT_bf  = (unsigned short*)alloc((size_t)B * H * QL * 2);    // 1.05 MB
  float* pct   = (float*)alloc((size_t)2 * B * CL * sizeof(float));
  float* pqt   = (float*)alloc((size_t)2 * B * QL * sizeof(float));
  float* rsum_ = (float*)alloc((size_t)B * CL * sizeof(float));
  float* Lpart = (float*)alloc((size_t)B * 64 * QL * sizeof(float));          // 1 MB

  ktrans_all<<<dim3(CL / 64 + QL / 64, H / 64, B), dim3(256), 0, stream>>>(
      context, question, w, ctx_bf, ctxwT, qry_bf, qryT, pct, pqt, out);

  k2_score2<<<dim3(CL / 32, B), dim3(512), 0, stream>>>(
      ctxwT, qryT, pct, pqt, c_mask, q_mask, s1u, s2u, rsum_, Lpart);

  k5_tpart<<<dim3(QL / 32, SPLITK5, B), dim3(256), 0, stream>>>(
      s2u, ctx_bf, tpart);

  k5b_treduce<<<dim3(QL / 64, H / 32, B), dim3(256), 0, stream>>>(
      tpart, Lpart, tT_bf);

  kb_out<<<dim3(CL / 64, B), dim3(512), 0, stream>>>(
      s1u, qry_bf, tT_bf, ctx_bf, rsum_, out);
}